// Round 10
// baseline (251.362 us; speedup 1.0000x reference)
//
#include <hip/hip_runtime.h>
#include <hip/hip_fp16.h>
#include <stdint.h>

// DistMult relational decoder:
//   out[e] = sigmoid( sum_d z[src[e],d] * rel[rel_id[e],d] * z[dst[e],d] )
// N_NODES=100000, E=2000000, D=128, REL_TYPES=64, fp32 in/out.
//
// R10: R9 found the bucketed main kernel at 2.58 TB/s (below the 3.45
// ceiling) with a hidden cost: 74k blocks x 16 KB rel_lds staging = 1.2 GB
// of TCC traffic + syncthreads + 2M LDS bank-conflict cycles. rel fp16 is
// 16 KB -> L1-resident; read it directly per edge (no LDS, no barrier).
// 4 edges per 8-lane group (128 edges/block): 4x fewer blocks, 16
// independent z-gathers in flight per lane. Scatter unchanged from R9.

#define NSRC 8
#define NDST 64
#define NBKT 512        // NSRC * NDST
#define CNT_STRIDE 16   // one counter per 64 B line
#define SC_BLOCKS 512
#define PE 16           // edges per scatter thread
#define EPB 128         // edges per main-kernel block

#if defined(__has_builtin)
#if __has_builtin(__builtin_amdgcn_fdot2)
#define HAS_FDOT2 1
#endif
#endif

typedef _Float16 hv2 __attribute__((ext_vector_type(2)));

// acc += sum over 2 packed elems of a*r*b (fp16 inputs, fp32 accumulate)
__device__ __forceinline__ float dot3_accum(uint32_t a, uint32_t r, uint32_t b,
                                            float acc)
{
#ifdef HAS_FDOT2
    union { uint32_t u; hv2 v; } A, R, B;
    A.u = a; R.u = r; B.u = b;
    const hv2 t = A.v * R.v;                            // v_pk_mul_f16
    return __builtin_amdgcn_fdot2(t, B.v, acc, false);  // v_dot2_f32_f16
#else
    union { uint32_t u; __half2 h; } A, R, B;
    A.u = a; R.u = r; B.u = b;
    const float2 af = __half22float2(A.h);
    const float2 rf = __half22float2(R.h);
    const float2 bf = __half22float2(B.h);
    acc = fmaf(af.x * rf.x, bf.x, acc);
    acc = fmaf(af.y * rf.y, bf.y, acc);
    return acc;
#endif
}

// ---- fp32 -> fp16 converter (8 elems / thread), used for z and rel ----
__global__ __launch_bounds__(256) void convert_kernel(
    const float* __restrict__ x, __half* __restrict__ xh, int n8)
{
    const int i = blockIdx.x * blockDim.x + threadIdx.x;
    if (i >= n8) return;
    const float4 f0 = ((const float4*)x)[2 * i];
    const float4 f1 = ((const float4*)x)[2 * i + 1];
    union { __half2 h2[4]; uint4 u; } o;
    o.h2[0] = __floats2half2_rn(f0.x, f0.y);
    o.h2[1] = __floats2half2_rn(f0.z, f0.w);
    o.h2[2] = __floats2half2_rn(f1.x, f1.y);
    o.h2[3] = __floats2half2_rn(f1.z, f1.w);
    ((uint4*)xh)[i] = o.u;
}

__device__ __forceinline__ uint32_t bucket_of2(uint32_t s, uint32_t d, uint32_t nn) {
    uint32_t ss = (s * (uint32_t)NSRC) / nn; if (ss > NSRC - 1) ss = NSRC - 1;
    uint32_t ds = (d * (uint32_t)NDST) / nn; if (ds > NDST - 1) ds = NDST - 1;
    return ss * NDST + ds;
}

// ---- LDS-aggregated bucketing scatter, register-held edges (R9) ----
__global__ __launch_bounds__(256) void scatter_reg_kernel(
    const int* __restrict__ src, const int* __restrict__ dst,
    const int* __restrict__ relid, int E, int nn, int cap,
    uint32_t* __restrict__ counters, uint64_t* __restrict__ binned)
{
    __shared__ uint32_t hist[NBKT];
    __shared__ uint32_t cursor[NBKT];

    const int chunk = (E + (int)gridDim.x - 1) / (int)gridDim.x;
    const int lo = blockIdx.x * chunk;
    const int hi = (lo + chunk < E) ? lo + chunk : E;

    for (int t = threadIdx.x; t < NBKT; t += 256) hist[t] = 0;
    __syncthreads();

    uint64_t pay[PE];
    uint32_t bkt[PE];

    #pragma unroll
    for (int p = 0; p < PE; p++) {
        const int i = lo + p * 256 + (int)threadIdx.x;
        if (i < hi) {
            const uint32_t s = (uint32_t)src[i];
            const uint32_t d = (uint32_t)dst[i];
            const uint32_t r = (uint32_t)relid[i];
            const uint32_t b = bucket_of2(s, d, (uint32_t)nn);
            pay[p] = (uint64_t)s | ((uint64_t)d << 17)
                   | ((uint64_t)r << 34) | ((uint64_t)i << 40);
            bkt[p] = b;
            atomicAdd(&hist[b], 1u);
        } else {
            bkt[p] = 0xFFFFFFFFu;
        }
    }
    __syncthreads();

    for (int t = threadIdx.x; t < NBKT; t += 256) {
        const uint32_t c = hist[t];
        cursor[t] = c ? atomicAdd(&counters[t * CNT_STRIDE], c) : 0u;
    }
    __syncthreads();

    #pragma unroll
    for (int p = 0; p < PE; p++) {
        if (bkt[p] != 0xFFFFFFFFu) {
            const uint32_t pos = atomicAdd(&cursor[bkt[p]], 1u);   // LDS atomic
            if (pos < (uint32_t)cap)
                binned[(size_t)bkt[p] * (size_t)cap + pos] = pay[p];
        }
    }
}

// ---- main: bucket (k=blockIdx&7, j in order), 8 lanes/edge, 4 edges/group
__global__ __launch_bounds__(256) void distmult_bucketed4_kernel(
    const __half* __restrict__ zh,
    const uint64_t* __restrict__ binned,
    const uint32_t* __restrict__ counters,
    const __half* __restrict__ relh,   // [64*128] fp16, L1-resident (16 KB)
    float* __restrict__ out,
    int cap, int cpb)                  // cpb = blocks per bucket (EPB edges each)
{
    const int k     = blockIdx.x & 7;          // src-slice == XCD affinity
    const int t     = blockIdx.x >> 3;
    const int j     = t / cpb;                 // dst-slice, increases with time
    const int chunk = t - j * cpb;
    const int bkt   = k * NDST + j;

    uint32_t cnt = counters[bkt * CNT_STRIDE];
    if (cnt > (uint32_t)cap) cnt = (uint32_t)cap;
    const uint32_t el_blk = (uint32_t)chunk * (uint32_t)EPB;
    if (el_blk >= cnt) return;                 // block-uniform early exit

    const int g    = threadIdx.x >> 3;         // 0..31: edge group
    const int lane = threadIdx.x & 7;          // 0..7 within edge

    const uint64_t* bb = binned + (size_t)bkt * (size_t)cap;
    const uint32_t e_base = el_blk + (uint32_t)g * 4u;

    union U4 { uint4 q; uint32_t w[4]; };
    float acc[4];
    uint32_t eid[4];
    bool valid[4];

    #pragma unroll
    for (int i = 0; i < 4; i++) {
        const uint32_t el = e_base + (uint32_t)i;
        valid[i] = (el < cnt);
        const uint64_t p = bb[valid[i] ? el : 0];
        const uint32_t s = (uint32_t)p & 0x1FFFFu;
        const uint32_t d = (uint32_t)(p >> 17) & 0x1FFFFu;
        const uint32_t r = (uint32_t)(p >> 34) & 0x3Fu;
        eid[i] = (uint32_t)(p >> 40);

        const uint4* sb = (const uint4*)(zh + (size_t)s * 128);
        const uint4* db = (const uint4*)(zh + (size_t)d * 128);
        const uint4* rb = (const uint4*)(relh + (size_t)r * 128);
        U4 A0, A1, B0, B1, R0, R1;
        A0.q = sb[lane * 2];
        A1.q = sb[lane * 2 + 1];
        B0.q = db[lane * 2];
        B1.q = db[lane * 2 + 1];
        R0.q = rb[lane * 2];        // L1 hit (rel fp16 = 16 KB)
        R1.q = rb[lane * 2 + 1];

        float a = 0.f;
        #pragma unroll
        for (int q = 0; q < 4; q++) {
            a = dot3_accum(A0.w[q], R0.w[q], B0.w[q], a);
            a = dot3_accum(A1.w[q], R1.w[q], B1.w[q], a);
        }
        acc[i] = a;
    }

    // reduce across the 8 lanes of each edge
    #pragma unroll
    for (int off = 4; off > 0; off >>= 1) {
        #pragma unroll
        for (int i = 0; i < 4; i++)
            acc[i] += __shfl_down(acc[i], off, 8);
    }

    if (lane == 0) {
        #pragma unroll
        for (int i = 0; i < 4; i++)
            if (valid[i])
                out[eid[i]] = 1.0f / (1.0f + __expf(-acc[i]));
    }
}

// ---- fallback: R6 kernel (z fp16 gathers, rel fp16 LDS, natural order) ----
__global__ __launch_bounds__(256) void distmult_f16_lds_kernel(
    const __half* __restrict__ zh,
    const int* __restrict__ src_idx, const int* __restrict__ dst_idx,
    const int* __restrict__ rel_id, const __half* __restrict__ relh,
    float* __restrict__ out, int E)
{
    const int gtid = blockIdx.x * blockDim.x + threadIdx.x;
    const int g = gtid >> 4;
    const int lane = threadIdx.x & 15;
    const int e0 = g * 2, e1 = e0 + 1;
    if (e0 >= E) return;
    const bool has1 = (e1 < E);

    const int s0 = src_idx[e0], d0 = dst_idx[e0], r0 = rel_id[e0];
    const int s1 = has1 ? src_idx[e1] : s0;
    const int d1 = has1 ? dst_idx[e1] : d0;
    const int r1 = has1 ? rel_id[e1]  : r0;

    union U4 { uint4 q; uint32_t w[4]; };
    U4 A0, B0, A1, B1, R0, R1;
    A0.q = ((const uint4*)(zh + (size_t)s0 * 128))[lane];
    B0.q = ((const uint4*)(zh + (size_t)d0 * 128))[lane];
    A1.q = ((const uint4*)(zh + (size_t)s1 * 128))[lane];
    B1.q = ((const uint4*)(zh + (size_t)d1 * 128))[lane];
    R0.q = ((const uint4*)(relh + (size_t)r0 * 128))[lane];
    R1.q = ((const uint4*)(relh + (size_t)r1 * 128))[lane];

    float v0 = 0.f, v1 = 0.f;
    #pragma unroll
    for (int q = 0; q < 4; q++) {
        v0 = dot3_accum(A0.w[q], R0.w[q], B0.w[q], v0);
        v1 = dot3_accum(A1.w[q], R1.w[q], B1.w[q], v1);
    }
    #pragma unroll
    for (int off = 8; off > 0; off >>= 1) {
        v0 += __shfl_down(v0, off, 16);
        v1 += __shfl_down(v1, off, 16);
    }
    if (lane == 0) {
        const float o0 = 1.0f / (1.0f + __expf(-v0));
        if (has1) {
            const float o1 = 1.0f / (1.0f + __expf(-v1));
            *((float2*)(out + e0)) = make_float2(o0, o1);
        } else {
            out[e0] = o0;
        }
    }
}

// ---- fallback: pure fp32 ----
__global__ __launch_bounds__(256) void distmult_f32_kernel(
    const float* __restrict__ z,
    const int* __restrict__ src_idx, const int* __restrict__ dst_idx,
    const int* __restrict__ rel_id, const float* __restrict__ rel,
    float* __restrict__ out, int E)
{
    const int gtid = blockIdx.x * blockDim.x + threadIdx.x;
    const int e = gtid >> 4;
    const int lane = threadIdx.x & 15;
    if (e >= E) return;
    const int s = src_idx[e], d = dst_idx[e], r = rel_id[e];
    const float4* zs = (const float4*)(z + (size_t)s * 128);
    const float4* zd = (const float4*)(z + (size_t)d * 128);
    const float4* rr = (const float4*)(rel + (size_t)r * 128);
    const float4 a0 = zs[lane], a1 = zs[lane + 16];
    const float4 b0 = zd[lane], b1 = zd[lane + 16];
    const float4 c0 = rr[lane], c1 = rr[lane + 16];
    float v = a0.x * c0.x * b0.x + a0.y * c0.y * b0.y
            + a0.z * c0.z * b0.z + a0.w * c0.w * b0.w
            + a1.x * c1.x * b1.x + a1.y * c1.y * b1.y
            + a1.z * c1.z * b1.z + a1.w * c1.w * b1.w;
    #pragma unroll
    for (int off = 8; off > 0; off >>= 1) v += __shfl_down(v, off, 16);
    if (lane == 0) out[e] = 1.0f / (1.0f + __expf(-v));
}

extern "C" void kernel_launch(void* const* d_in, const int* in_sizes, int n_in,
                              void* d_out, int out_size, void* d_ws, size_t ws_size,
                              hipStream_t stream) {
    const float* z     = (const float*)d_in[0];
    const int*   eidx  = (const int*)d_in[1];   // [2, E] flat: src then dst
    const int*   relid = (const int*)d_in[2];
    const float* rel   = (const float*)d_in[3];
    float*       out   = (float*)d_out;

    const int nz   = in_sizes[0];        // N_NODES * 128
    const int E    = in_sizes[2];        // 2,000,000
    const int nrel = in_sizes[3];        // 64 * 128
    const int nn   = nz / 128;           // N_NODES
    const int* src = eidx;
    const int* dst = eidx + E;

    // bucket capacity: mean + ~12 sigma, rounded to EPB
    const int mean_b = E / NBKT;
    int cap = mean_b + E / 8192 + 512;
    cap = (cap + EPB - 1) & ~(EPB - 1);
    const int cpb = cap / EPB;           // blocks per bucket

    const int sc_blocks = ((E + PE * 256 - 1) / (PE * 256) > SC_BLOCKS)
                        ? (E + PE * 256 - 1) / (PE * 256) : SC_BLOCKS;

    // ws layout
    const size_t sz_zh    = (size_t)nz * sizeof(__half);
    const size_t off_rh   = (sz_zh + 255) & ~(size_t)255;
    const size_t sz_rh    = (size_t)nrel * sizeof(__half);
    const size_t off_cnt  = (off_rh + sz_rh + 255) & ~(size_t)255;
    const size_t sz_cnt   = (size_t)NBKT * CNT_STRIDE * 4;   // 32 KB
    const size_t off_bin  = (off_cnt + sz_cnt + 255) & ~(size_t)255;
    const size_t sz_bin   = (size_t)NBKT * (size_t)cap * 8;
    const size_t need     = off_bin + sz_bin;

    const bool rel_ok  = (nrel == 64 * 128);
    const bool bits_ok = (nn <= 131072) && (E <= (1 << 21)) && (nz % 8 == 0);

    if (ws_size >= need && rel_ok && bits_ok) {
        char* ws = (char*)d_ws;
        __half*   zh       = (__half*)(ws);
        __half*   rh       = (__half*)(ws + off_rh);
        uint32_t* counters = (uint32_t*)(ws + off_cnt);
        uint64_t* binned   = (uint64_t*)(ws + off_bin);

        const int n8z = nz / 8, n8r = nrel / 8;
        convert_kernel<<<(n8z + 255) / 256, 256, 0, stream>>>(z, zh, n8z);
        convert_kernel<<<(n8r + 255) / 256, 256, 0, stream>>>(rel, rh, n8r);
        hipMemsetAsync(counters, 0, sz_cnt, stream);
        scatter_reg_kernel<<<sc_blocks, 256, 0, stream>>>(
            src, dst, relid, E, nn, cap, counters, binned);
        distmult_bucketed4_kernel<<<NSRC * NDST * cpb, 256, 0, stream>>>(
            zh, binned, counters, rh, out, cap, cpb);
    } else if (ws_size >= off_rh + sz_rh && rel_ok && nz % 8 == 0) {
        __half* zh = (__half*)d_ws;
        __half* rh = (__half*)((char*)d_ws + off_rh);
        const int n8z = nz / 8, n8r = nrel / 8;
        convert_kernel<<<(n8z + 255) / 256, 256, 0, stream>>>(z, zh, n8z);
        convert_kernel<<<(n8r + 255) / 256, 256, 0, stream>>>(rel, rh, n8r);
        const int groups = (E + 1) / 2;
        const int blocks = (groups * 16 + 255) / 256;
        distmult_f16_lds_kernel<<<blocks, 256, 0, stream>>>(
            zh, src, dst, relid, rh, out, E);
    } else {
        const int blocks = (E * 16 + 255) / 256;
        distmult_f32_kernel<<<blocks, 256, 0, stream>>>(z, src, dst, relid, rel, out, E);
    }
}

// Round 11
// 217.495 us; speedup vs baseline: 1.1557x; 1.1557x over previous
//
#include <hip/hip_runtime.h>
#include <hip/hip_fp16.h>
#include <stdint.h>

// DistMult relational decoder:
//   out[e] = sigmoid( sum_d z[src[e],d] * rel[rel_id[e],d] * z[dst[e],d] )
// N_NODES=100000, E=2000000, D=128, REL_TYPES=64, fp32 in/out.
//
// R11: R10 disproved "staging was the cost" (direct rel gathers regressed
// 105->115). Revised model: R9 main = 78.5 us fabric (271 MB @ 3.45 TB/s)
// + ~27 us LDS-staging overhead (32 edges/block -> 74.7k blocks x 16 KB =
// 1.19 GB L2 reads). Fix: keep rel in LDS (R10's lesson) but amortize
// staging with 128 edges/block (4 edges per 8-lane group, register-
// blocked) -> ~310 MB staging. Loads use [lane],[lane+8] so each VMEM
// instruction covers contiguous 128 B per edge (R10 used stride-32).
// Scatter unchanged from R9 (~29 us known).

#define NSRC 8
#define NDST 64
#define NBKT 512        // NSRC * NDST
#define CNT_STRIDE 16   // one counter per 64 B line
#define SC_BLOCKS 512
#define PE 16           // edges per scatter thread
#define EPB 128         // edges per main-kernel block

#if defined(__has_builtin)
#if __has_builtin(__builtin_amdgcn_fdot2)
#define HAS_FDOT2 1
#endif
#endif

typedef _Float16 hv2 __attribute__((ext_vector_type(2)));

// acc += sum over 2 packed elems of a*r*b (fp16 inputs, fp32 accumulate)
__device__ __forceinline__ float dot3_accum(uint32_t a, uint32_t r, uint32_t b,
                                            float acc)
{
#ifdef HAS_FDOT2
    union { uint32_t u; hv2 v; } A, R, B;
    A.u = a; R.u = r; B.u = b;
    const hv2 t = A.v * R.v;                            // v_pk_mul_f16
    return __builtin_amdgcn_fdot2(t, B.v, acc, false);  // v_dot2_f32_f16
#else
    union { uint32_t u; __half2 h; } A, R, B;
    A.u = a; R.u = r; B.u = b;
    const float2 af = __half22float2(A.h);
    const float2 rf = __half22float2(R.h);
    const float2 bf = __half22float2(B.h);
    acc = fmaf(af.x * rf.x, bf.x, acc);
    acc = fmaf(af.y * rf.y, bf.y, acc);
    return acc;
#endif
}

// ---- fp32 -> fp16 converter (8 elems / thread), used for z and rel ----
__global__ __launch_bounds__(256) void convert_kernel(
    const float* __restrict__ x, __half* __restrict__ xh, int n8)
{
    const int i = blockIdx.x * blockDim.x + threadIdx.x;
    if (i >= n8) return;
    const float4 f0 = ((const float4*)x)[2 * i];
    const float4 f1 = ((const float4*)x)[2 * i + 1];
    union { __half2 h2[4]; uint4 u; } o;
    o.h2[0] = __floats2half2_rn(f0.x, f0.y);
    o.h2[1] = __floats2half2_rn(f0.z, f0.w);
    o.h2[2] = __floats2half2_rn(f1.x, f1.y);
    o.h2[3] = __floats2half2_rn(f1.z, f1.w);
    ((uint4*)xh)[i] = o.u;
}

__device__ __forceinline__ uint32_t bucket_of2(uint32_t s, uint32_t d, uint32_t nn) {
    uint32_t ss = (s * (uint32_t)NSRC) / nn; if (ss > NSRC - 1) ss = NSRC - 1;
    uint32_t ds = (d * (uint32_t)NDST) / nn; if (ds > NDST - 1) ds = NDST - 1;
    return ss * NDST + ds;
}

// ---- LDS-aggregated bucketing scatter, register-held edges (R9) ----
__global__ __launch_bounds__(256) void scatter_reg_kernel(
    const int* __restrict__ src, const int* __restrict__ dst,
    const int* __restrict__ relid, int E, int nn, int cap,
    uint32_t* __restrict__ counters, uint64_t* __restrict__ binned)
{
    __shared__ uint32_t hist[NBKT];
    __shared__ uint32_t cursor[NBKT];

    const int chunk = (E + (int)gridDim.x - 1) / (int)gridDim.x;
    const int lo = blockIdx.x * chunk;
    const int hi = (lo + chunk < E) ? lo + chunk : E;

    for (int t = threadIdx.x; t < NBKT; t += 256) hist[t] = 0;
    __syncthreads();

    uint64_t pay[PE];
    uint32_t bkt[PE];

    #pragma unroll
    for (int p = 0; p < PE; p++) {
        const int i = lo + p * 256 + (int)threadIdx.x;
        if (i < hi) {
            const uint32_t s = (uint32_t)src[i];
            const uint32_t d = (uint32_t)dst[i];
            const uint32_t r = (uint32_t)relid[i];
            const uint32_t b = bucket_of2(s, d, (uint32_t)nn);
            pay[p] = (uint64_t)s | ((uint64_t)d << 17)
                   | ((uint64_t)r << 34) | ((uint64_t)i << 40);
            bkt[p] = b;
            atomicAdd(&hist[b], 1u);
        } else {
            bkt[p] = 0xFFFFFFFFu;
        }
    }
    __syncthreads();

    for (int t = threadIdx.x; t < NBKT; t += 256) {
        const uint32_t c = hist[t];
        cursor[t] = c ? atomicAdd(&counters[t * CNT_STRIDE], c) : 0u;
    }
    __syncthreads();

    #pragma unroll
    for (int p = 0; p < PE; p++) {
        if (bkt[p] != 0xFFFFFFFFu) {
            const uint32_t pos = atomicAdd(&cursor[bkt[p]], 1u);   // LDS atomic
            if (pos < (uint32_t)cap)
                binned[(size_t)bkt[p] * (size_t)cap + pos] = pay[p];
        }
    }
}

// ---- main: bucket (k=blockIdx&7, j in order), 8 lanes/edge, 4 edges/group,
//      128 edges/block, rel staged once per block in LDS ----
__global__ __launch_bounds__(256) void distmult_bucketed_v3_kernel(
    const __half* __restrict__ zh,
    const uint64_t* __restrict__ binned,
    const uint32_t* __restrict__ counters,
    const __half* __restrict__ relh,   // [64*128] fp16
    float* __restrict__ out,
    int cap, int cpb)                  // cpb = blocks per bucket (EPB edges each)
{
    const int k     = blockIdx.x & 7;          // src-slice == XCD affinity
    const int t     = blockIdx.x >> 3;
    const int j     = t / cpb;                 // dst-slice, increases with time
    const int chunk = t - j * cpb;
    const int bkt   = k * NDST + j;

    uint32_t cnt = counters[bkt * CNT_STRIDE];
    if (cnt > (uint32_t)cap) cnt = (uint32_t)cap;
    const uint32_t el_blk = (uint32_t)chunk * (uint32_t)EPB;
    if (el_blk >= cnt) return;                 // block-uniform early exit

    __shared__ uint4 rel_lds[1024];            // 64 rows * 16 uint4 = 16 KB
    {
        const uint4* rsrc = (const uint4*)relh;
        #pragma unroll
        for (int q = 0; q < 4; q++)
            rel_lds[threadIdx.x + 256 * q] = rsrc[threadIdx.x + 256 * q];
    }
    __syncthreads();

    const int g    = threadIdx.x >> 3;         // 0..31: edge group
    const int lane = threadIdx.x & 7;          // 0..7 within edge

    const uint64_t* bb = binned + (size_t)bkt * (size_t)cap;
    const uint32_t e_base = el_blk + (uint32_t)g * 4u;

    union U4 { uint4 q; uint32_t w[4]; };
    float acc[4];
    uint32_t eid[4];
    bool valid[4];

    #pragma unroll
    for (int i = 0; i < 4; i++) {
        const uint32_t el = e_base + (uint32_t)i;
        valid[i] = (el < cnt);
        const uint64_t p = bb[valid[i] ? el : 0];
        const uint32_t s = (uint32_t)p & 0x1FFFFu;
        const uint32_t d = (uint32_t)(p >> 17) & 0x1FFFFu;
        const uint32_t r = (uint32_t)(p >> 34) & 0x3Fu;
        eid[i] = (uint32_t)(p >> 40);

        // contiguous pattern: lanes 0..7 cover 128 B, then next 128 B
        const uint4* sb = (const uint4*)(zh + (size_t)s * 128);
        const uint4* db = (const uint4*)(zh + (size_t)d * 128);
        U4 A0, A1, B0, B1, R0, R1;
        A0.q = sb[lane];
        A1.q = sb[lane + 8];
        B0.q = db[lane];
        B1.q = db[lane + 8];
        R0.q = rel_lds[r * 16 + lane];
        R1.q = rel_lds[r * 16 + lane + 8];

        float a = 0.f;
        #pragma unroll
        for (int q = 0; q < 4; q++) {
            a = dot3_accum(A0.w[q], R0.w[q], B0.w[q], a);
            a = dot3_accum(A1.w[q], R1.w[q], B1.w[q], a);
        }
        acc[i] = a;
    }

    // reduce across the 8 lanes of each edge
    #pragma unroll
    for (int off = 4; off > 0; off >>= 1) {
        #pragma unroll
        for (int i = 0; i < 4; i++)
            acc[i] += __shfl_down(acc[i], off, 8);
    }

    if (lane == 0) {
        #pragma unroll
        for (int i = 0; i < 4; i++)
            if (valid[i])
                out[eid[i]] = 1.0f / (1.0f + __expf(-acc[i]));
    }
}

// ---- fallback: R6-style (z fp16 gathers, rel fp16 direct, natural order) ----
__global__ __launch_bounds__(256) void distmult_f16_kernel(
    const __half* __restrict__ zh,
    const int* __restrict__ src_idx, const int* __restrict__ dst_idx,
    const int* __restrict__ rel_id, const __half* __restrict__ relh,
    float* __restrict__ out, int E)
{
    const int gtid = blockIdx.x * blockDim.x + threadIdx.x;
    const int g = gtid >> 4;
    const int lane = threadIdx.x & 15;
    const int e0 = g * 2, e1 = e0 + 1;
    if (e0 >= E) return;
    const bool has1 = (e1 < E);

    const int s0 = src_idx[e0], d0 = dst_idx[e0], r0 = rel_id[e0];
    const int s1 = has1 ? src_idx[e1] : s0;
    const int d1 = has1 ? dst_idx[e1] : d0;
    const int r1 = has1 ? rel_id[e1]  : r0;

    union U4 { uint4 q; uint32_t w[4]; };
    U4 A0, B0, A1, B1, R0, R1;
    A0.q = ((const uint4*)(zh + (size_t)s0 * 128))[lane];
    B0.q = ((const uint4*)(zh + (size_t)d0 * 128))[lane];
    A1.q = ((const uint4*)(zh + (size_t)s1 * 128))[lane];
    B1.q = ((const uint4*)(zh + (size_t)d1 * 128))[lane];
    R0.q = ((const uint4*)(relh + (size_t)r0 * 128))[lane];
    R1.q = ((const uint4*)(relh + (size_t)r1 * 128))[lane];

    float v0 = 0.f, v1 = 0.f;
    #pragma unroll
    for (int q = 0; q < 4; q++) {
        v0 = dot3_accum(A0.w[q], R0.w[q], B0.w[q], v0);
        v1 = dot3_accum(A1.w[q], R1.w[q], B1.w[q], v1);
    }
    #pragma unroll
    for (int off = 8; off > 0; off >>= 1) {
        v0 += __shfl_down(v0, off, 16);
        v1 += __shfl_down(v1, off, 16);
    }
    if (lane == 0) {
        const float o0 = 1.0f / (1.0f + __expf(-v0));
        if (has1) {
            const float o1 = 1.0f / (1.0f + __expf(-v1));
            *((float2*)(out + e0)) = make_float2(o0, o1);
        } else {
            out[e0] = o0;
        }
    }
}

// ---- fallback: pure fp32 ----
__global__ __launch_bounds__(256) void distmult_f32_kernel(
    const float* __restrict__ z,
    const int* __restrict__ src_idx, const int* __restrict__ dst_idx,
    const int* __restrict__ rel_id, const float* __restrict__ rel,
    float* __restrict__ out, int E)
{
    const int gtid = blockIdx.x * blockDim.x + threadIdx.x;
    const int e = gtid >> 4;
    const int lane = threadIdx.x & 15;
    if (e >= E) return;
    const int s = src_idx[e], d = dst_idx[e], r = rel_id[e];
    const float4* zs = (const float4*)(z + (size_t)s * 128);
    const float4* zd = (const float4*)(z + (size_t)d * 128);
    const float4* rr = (const float4*)(rel + (size_t)r * 128);
    const float4 a0 = zs[lane], a1 = zs[lane + 16];
    const float4 b0 = zd[lane], b1 = zd[lane + 16];
    const float4 c0 = rr[lane], c1 = rr[lane + 16];
    float v = a0.x * c0.x * b0.x + a0.y * c0.y * b0.y
            + a0.z * c0.z * b0.z + a0.w * c0.w * b0.w
            + a1.x * c1.x * b1.x + a1.y * c1.y * b1.y
            + a1.z * c1.z * b1.z + a1.w * c1.w * b1.w;
    #pragma unroll
    for (int off = 8; off > 0; off >>= 1) v += __shfl_down(v, off, 16);
    if (lane == 0) out[e] = 1.0f / (1.0f + __expf(-v));
}

extern "C" void kernel_launch(void* const* d_in, const int* in_sizes, int n_in,
                              void* d_out, int out_size, void* d_ws, size_t ws_size,
                              hipStream_t stream) {
    const float* z     = (const float*)d_in[0];
    const int*   eidx  = (const int*)d_in[1];   // [2, E] flat: src then dst
    const int*   relid = (const int*)d_in[2];
    const float* rel   = (const float*)d_in[3];
    float*       out   = (float*)d_out;

    const int nz   = in_sizes[0];        // N_NODES * 128
    const int E    = in_sizes[2];        // 2,000,000
    const int nrel = in_sizes[3];        // 64 * 128
    const int nn   = nz / 128;           // N_NODES
    const int* src = eidx;
    const int* dst = eidx + E;

    // bucket capacity: mean + ~13 sigma, rounded to EPB
    const int mean_b = E / NBKT;
    int cap = mean_b + E / 8192 + 512;
    cap = (cap + EPB - 1) & ~(EPB - 1);
    const int cpb = cap / EPB;           // blocks per bucket

    const int sc_blocks = ((E + PE * 256 - 1) / (PE * 256) > SC_BLOCKS)
                        ? (E + PE * 256 - 1) / (PE * 256) : SC_BLOCKS;

    // ws layout
    const size_t sz_zh    = (size_t)nz * sizeof(__half);
    const size_t off_rh   = (sz_zh + 255) & ~(size_t)255;
    const size_t sz_rh    = (size_t)nrel * sizeof(__half);
    const size_t off_cnt  = (off_rh + sz_rh + 255) & ~(size_t)255;
    const size_t sz_cnt   = (size_t)NBKT * CNT_STRIDE * 4;   // 32 KB
    const size_t off_bin  = (off_cnt + sz_cnt + 255) & ~(size_t)255;
    const size_t sz_bin   = (size_t)NBKT * (size_t)cap * 8;
    const size_t need     = off_bin + sz_bin;

    const bool rel_ok  = (nrel == 64 * 128);
    const bool bits_ok = (nn <= 131072) && (E <= (1 << 21)) && (nz % 8 == 0);

    if (ws_size >= need && rel_ok && bits_ok) {
        char* ws = (char*)d_ws;
        __half*   zh       = (__half*)(ws);
        __half*   rh       = (__half*)(ws + off_rh);
        uint32_t* counters = (uint32_t*)(ws + off_cnt);
        uint64_t* binned   = (uint64_t*)(ws + off_bin);

        const int n8z = nz / 8, n8r = nrel / 8;
        convert_kernel<<<(n8z + 255) / 256, 256, 0, stream>>>(z, zh, n8z);
        convert_kernel<<<(n8r + 255) / 256, 256, 0, stream>>>(rel, rh, n8r);
        hipMemsetAsync(counters, 0, sz_cnt, stream);
        scatter_reg_kernel<<<sc_blocks, 256, 0, stream>>>(
            src, dst, relid, E, nn, cap, counters, binned);
        distmult_bucketed_v3_kernel<<<NSRC * NDST * cpb, 256, 0, stream>>>(
            zh, binned, counters, rh, out, cap, cpb);
    } else if (ws_size >= off_rh + sz_rh && rel_ok && nz % 8 == 0) {
        __half* zh = (__half*)d_ws;
        __half* rh = (__half*)((char*)d_ws + off_rh);
        const int n8z = nz / 8, n8r = nrel / 8;
        convert_kernel<<<(n8z + 255) / 256, 256, 0, stream>>>(z, zh, n8z);
        convert_kernel<<<(n8r + 255) / 256, 256, 0, stream>>>(rel, rh, n8r);
        const int groups = (E + 1) / 2;
        const int blocks = (groups * 16 + 255) / 256;
        distmult_f16_kernel<<<blocks, 256, 0, stream>>>(
            zh, src, dst, relid, rh, out, E);
    } else {
        const int blocks = (E * 16 + 255) / 256;
        distmult_f32_kernel<<<blocks, 256, 0, stream>>>(z, src, dst, relid, rel, out, E);
    }
}

// Round 12
// 216.152 us; speedup vs baseline: 1.1629x; 1.0062x over previous
//
#include <hip/hip_runtime.h>
#include <hip/hip_fp16.h>
#include <stdint.h>

// DistMult relational decoder:
//   out[e] = sigmoid( sum_d z[src[e],d] * rel[rel_id[e],d] * z[dst[e],d] )
// N_NODES=100000, E=2000000, D=128, REL_TYPES=64, fp32 in/out.
//
// R12: R11 hit 217.5 total (main 85 us ~= its structural floor: 275 MB
// fabric @ 3.45 TB/s; dst x8-XCD re-read structural). Remaining fat: aux
// pipeline convert(13) + scatter(30, latency-bound at 2 blocks/CU) run
// sequentially on disjoint data. This round: ONE merged kernel — scatter
// blocks first (start immediately), convert blocks backfill (latency-bound
// scatter + BW-bound convert co-schedule, m114-style). Scatter TLP doubled
// (1024 blocks) with 2 counter replicas per bucket to keep per-counter
// atomic serialization constant. Main kernel: R11 structure, walks both
// replica regions per (src-slice, dst-phase).

#define NSRC 8
#define NDST 64
#define NBKT 512        // NSRC * NDST
#define NREP 2          // counter/region replicas per bucket
#define CNT_STRIDE 16   // one counter per 64 B line
#define PE 8            // edges per scatter thread
#define EPB 128         // edges per main-kernel block

#if defined(__has_builtin)
#if __has_builtin(__builtin_amdgcn_fdot2)
#define HAS_FDOT2 1
#endif
#endif

typedef _Float16 hv2 __attribute__((ext_vector_type(2)));

// acc += sum over 2 packed elems of a*r*b (fp16 inputs, fp32 accumulate)
__device__ __forceinline__ float dot3_accum(uint32_t a, uint32_t r, uint32_t b,
                                            float acc)
{
#ifdef HAS_FDOT2
    union { uint32_t u; hv2 v; } A, R, B;
    A.u = a; R.u = r; B.u = b;
    const hv2 t = A.v * R.v;                            // v_pk_mul_f16
    return __builtin_amdgcn_fdot2(t, B.v, acc, false);  // v_dot2_f32_f16
#else
    union { uint32_t u; __half2 h; } A, R, B;
    A.u = a; R.u = r; B.u = b;
    const float2 af = __half22float2(A.h);
    const float2 rf = __half22float2(R.h);
    const float2 bf = __half22float2(B.h);
    acc = fmaf(af.x * rf.x, bf.x, acc);
    acc = fmaf(af.y * rf.y, bf.y, acc);
    return acc;
#endif
}

__device__ __forceinline__ uint32_t bucket_of2(uint32_t s, uint32_t d, uint32_t nn) {
    uint32_t ss = (s * (uint32_t)NSRC) / nn; if (ss > NSRC - 1) ss = NSRC - 1;
    uint32_t ds = (d * (uint32_t)NDST) / nn; if (ds > NDST - 1) ds = NDST - 1;
    return ss * NDST + ds;
}

__device__ __forceinline__ void convert8(const float* __restrict__ x,
                                         __half* __restrict__ xh, int i)
{
    const float4 f0 = ((const float4*)x)[2 * i];
    const float4 f1 = ((const float4*)x)[2 * i + 1];
    union { __half2 h2[4]; uint4 u; } o;
    o.h2[0] = __floats2half2_rn(f0.x, f0.y);
    o.h2[1] = __floats2half2_rn(f0.z, f0.w);
    o.h2[2] = __floats2half2_rn(f1.x, f1.y);
    o.h2[3] = __floats2half2_rn(f1.z, f1.w);
    ((uint4*)xh)[i] = o.u;
}

// ---- merged aux kernel: [0,sc_blocks) scatter | then z-convert | rel-convert
// Scatter: LDS histogram of a contiguous chunk -> one global atomic per
// (block,bucket) on replica rep=blockIdx&1 (line-padded counters) ->
// LDS-cursor scatter into replica region. Within-bucket order
// nondeterministic; output order-invariant (each out[eid] written once).
__global__ __launch_bounds__(256) void aux_merged_kernel(
    const float* __restrict__ z, __half* __restrict__ zh, int n8z,
    const float* __restrict__ rel, __half* __restrict__ rh, int n8r,
    const int* __restrict__ src, const int* __restrict__ dst,
    const int* __restrict__ relid, int E, int nn, int vcap,
    uint32_t* __restrict__ counters, uint64_t* __restrict__ binned,
    int sc_blocks, int zc_blocks)
{
    const int bid = blockIdx.x;
    if (bid >= sc_blocks) {
        const int cb = bid - sc_blocks;
        if (cb < zc_blocks) {
            const int i = cb * 256 + (int)threadIdx.x;
            if (i < n8z) convert8(z, zh, i);
        } else {
            const int i = (cb - zc_blocks) * 256 + (int)threadIdx.x;
            if (i < n8r) convert8(rel, rh, i);
        }
        return;
    }

    // ---- scatter part ----
    __shared__ uint32_t hist[NBKT];
    __shared__ uint32_t cursor[NBKT];

    const int rep = bid & (NREP - 1);
    const int chunk = (E + sc_blocks - 1) / sc_blocks;
    const int lo = bid * chunk;
    const int hi = (lo + chunk < E) ? lo + chunk : E;

    for (int t = threadIdx.x; t < NBKT; t += 256) hist[t] = 0;
    __syncthreads();

    uint64_t pay[PE];
    uint32_t bkt[PE];

    #pragma unroll
    for (int p = 0; p < PE; p++) {
        const int i = lo + p * 256 + (int)threadIdx.x;
        if (i < hi) {
            const uint32_t s = (uint32_t)src[i];
            const uint32_t d = (uint32_t)dst[i];
            const uint32_t r = (uint32_t)relid[i];
            const uint32_t b = bucket_of2(s, d, (uint32_t)nn);
            pay[p] = (uint64_t)s | ((uint64_t)d << 17)
                   | ((uint64_t)r << 34) | ((uint64_t)i << 40);
            bkt[p] = b;
            atomicAdd(&hist[b], 1u);
        } else {
            bkt[p] = 0xFFFFFFFFu;
        }
    }
    __syncthreads();

    for (int t = threadIdx.x; t < NBKT; t += 256) {
        const uint32_t c = hist[t];
        cursor[t] = c ? atomicAdd(&counters[(t * NREP + rep) * CNT_STRIDE], c) : 0u;
    }
    __syncthreads();

    #pragma unroll
    for (int p = 0; p < PE; p++) {
        if (bkt[p] != 0xFFFFFFFFu) {
            const uint32_t pos = atomicAdd(&cursor[bkt[p]], 1u);   // LDS atomic
            if (pos < (uint32_t)vcap)
                binned[(size_t)(bkt[p] * NREP + rep) * (size_t)vcap + pos] = pay[p];
        }
    }
}

// ---- main: k=blockIdx&7 (XCD affinity), dst-phase j walked in order,
//      NREP replica regions per (k,j); 8 lanes/edge, 4 edges/group,
//      EPB edges/block, rel staged once per block in LDS ----
__global__ __launch_bounds__(256) void distmult_bucketed_v4_kernel(
    const __half* __restrict__ zh,
    const uint64_t* __restrict__ binned,
    const uint32_t* __restrict__ counters,
    const __half* __restrict__ relh,   // [64*128] fp16
    float* __restrict__ out,
    int vcap, int vcpb)                // vcpb = blocks per replica region
{
    const int k     = blockIdx.x & 7;          // src-slice == XCD affinity
    const int t     = blockIdx.x >> 3;
    const int per_j = NREP * vcpb;
    const int j     = t / per_j;               // dst-slice, increases with time
    const int rem   = t - j * per_j;
    const int rep   = rem / vcpb;
    const int chunk = rem - rep * vcpb;
    const int v     = (k * NDST + j) * NREP + rep;   // virtual bucket

    uint32_t cnt = counters[v * CNT_STRIDE];
    if (cnt > (uint32_t)vcap) cnt = (uint32_t)vcap;
    const uint32_t el_blk = (uint32_t)chunk * (uint32_t)EPB;
    if (el_blk >= cnt) return;                 // block-uniform early exit

    __shared__ uint4 rel_lds[1024];            // 64 rows * 16 uint4 = 16 KB
    {
        const uint4* rsrc = (const uint4*)relh;
        #pragma unroll
        for (int q = 0; q < 4; q++)
            rel_lds[threadIdx.x + 256 * q] = rsrc[threadIdx.x + 256 * q];
    }
    __syncthreads();

    const int g    = threadIdx.x >> 3;         // 0..31: edge group
    const int lane = threadIdx.x & 7;          // 0..7 within edge

    const uint64_t* bb = binned + (size_t)v * (size_t)vcap;
    const uint32_t e_base = el_blk + (uint32_t)g * 4u;

    union U4 { uint4 q; uint32_t w[4]; };
    float acc[4];
    uint32_t eid[4];
    bool valid[4];

    #pragma unroll
    for (int i = 0; i < 4; i++) {
        const uint32_t el = e_base + (uint32_t)i;
        valid[i] = (el < cnt);
        const uint64_t p = bb[valid[i] ? el : 0];
        const uint32_t s = (uint32_t)p & 0x1FFFFu;
        const uint32_t d = (uint32_t)(p >> 17) & 0x1FFFFu;
        const uint32_t r = (uint32_t)(p >> 34) & 0x3Fu;
        eid[i] = (uint32_t)(p >> 40);

        const uint4* sb = (const uint4*)(zh + (size_t)s * 128);
        const uint4* db = (const uint4*)(zh + (size_t)d * 128);
        U4 A0, A1, B0, B1, R0, R1;
        A0.q = sb[lane];
        A1.q = sb[lane + 8];
        B0.q = db[lane];
        B1.q = db[lane + 8];
        R0.q = rel_lds[r * 16 + lane];
        R1.q = rel_lds[r * 16 + lane + 8];

        float a = 0.f;
        #pragma unroll
        for (int q = 0; q < 4; q++) {
            a = dot3_accum(A0.w[q], R0.w[q], B0.w[q], a);
            a = dot3_accum(A1.w[q], R1.w[q], B1.w[q], a);
        }
        acc[i] = a;
    }

    #pragma unroll
    for (int off = 4; off > 0; off >>= 1) {
        #pragma unroll
        for (int i = 0; i < 4; i++)
            acc[i] += __shfl_down(acc[i], off, 8);
    }

    if (lane == 0) {
        #pragma unroll
        for (int i = 0; i < 4; i++)
            if (valid[i])
                out[eid[i]] = 1.0f / (1.0f + __expf(-acc[i]));
    }
}

// ---- fallback converter (standalone) ----
__global__ __launch_bounds__(256) void convert_kernel(
    const float* __restrict__ x, __half* __restrict__ xh, int n8)
{
    const int i = blockIdx.x * blockDim.x + threadIdx.x;
    if (i < n8) convert8(x, xh, i);
}

// ---- fallback: R6-style (z fp16 gathers, rel fp16 direct, natural order) ----
__global__ __launch_bounds__(256) void distmult_f16_kernel(
    const __half* __restrict__ zh,
    const int* __restrict__ src_idx, const int* __restrict__ dst_idx,
    const int* __restrict__ rel_id, const __half* __restrict__ relh,
    float* __restrict__ out, int E)
{
    const int gtid = blockIdx.x * blockDim.x + threadIdx.x;
    const int g = gtid >> 4;
    const int lane = threadIdx.x & 15;
    const int e0 = g * 2, e1 = e0 + 1;
    if (e0 >= E) return;
    const bool has1 = (e1 < E);

    const int s0 = src_idx[e0], d0 = dst_idx[e0], r0 = rel_id[e0];
    const int s1 = has1 ? src_idx[e1] : s0;
    const int d1 = has1 ? dst_idx[e1] : d0;
    const int r1 = has1 ? rel_id[e1]  : r0;

    union U4 { uint4 q; uint32_t w[4]; };
    U4 A0, B0, A1, B1, R0, R1;
    A0.q = ((const uint4*)(zh + (size_t)s0 * 128))[lane];
    B0.q = ((const uint4*)(zh + (size_t)d0 * 128))[lane];
    A1.q = ((const uint4*)(zh + (size_t)s1 * 128))[lane];
    B1.q = ((const uint4*)(zh + (size_t)d1 * 128))[lane];
    R0.q = ((const uint4*)(relh + (size_t)r0 * 128))[lane];
    R1.q = ((const uint4*)(relh + (size_t)r1 * 128))[lane];

    float v0 = 0.f, v1 = 0.f;
    #pragma unroll
    for (int q = 0; q < 4; q++) {
        v0 = dot3_accum(A0.w[q], R0.w[q], B0.w[q], v0);
        v1 = dot3_accum(A1.w[q], R1.w[q], B1.w[q], v1);
    }
    #pragma unroll
    for (int off = 8; off > 0; off >>= 1) {
        v0 += __shfl_down(v0, off, 16);
        v1 += __shfl_down(v1, off, 16);
    }
    if (lane == 0) {
        const float o0 = 1.0f / (1.0f + __expf(-v0));
        if (has1) {
            const float o1 = 1.0f / (1.0f + __expf(-v1));
            *((float2*)(out + e0)) = make_float2(o0, o1);
        } else {
            out[e0] = o0;
        }
    }
}

// ---- fallback: pure fp32 ----
__global__ __launch_bounds__(256) void distmult_f32_kernel(
    const float* __restrict__ z,
    const int* __restrict__ src_idx, const int* __restrict__ dst_idx,
    const int* __restrict__ rel_id, const float* __restrict__ rel,
    float* __restrict__ out, int E)
{
    const int gtid = blockIdx.x * blockDim.x + threadIdx.x;
    const int e = gtid >> 4;
    const int lane = threadIdx.x & 15;
    if (e >= E) return;
    const int s = src_idx[e], d = dst_idx[e], r = rel_id[e];
    const float4* zs = (const float4*)(z + (size_t)s * 128);
    const float4* zd = (const float4*)(z + (size_t)d * 128);
    const float4* rr = (const float4*)(rel + (size_t)r * 128);
    const float4 a0 = zs[lane], a1 = zs[lane + 16];
    const float4 b0 = zd[lane], b1 = zd[lane + 16];
    const float4 c0 = rr[lane], c1 = rr[lane + 16];
    float v = a0.x * c0.x * b0.x + a0.y * c0.y * b0.y
            + a0.z * c0.z * b0.z + a0.w * c0.w * b0.w
            + a1.x * c1.x * b1.x + a1.y * c1.y * b1.y
            + a1.z * c1.z * b1.z + a1.w * c1.w * b1.w;
    #pragma unroll
    for (int off = 8; off > 0; off >>= 1) v += __shfl_down(v, off, 16);
    if (lane == 0) out[e] = 1.0f / (1.0f + __expf(-v));
}

extern "C" void kernel_launch(void* const* d_in, const int* in_sizes, int n_in,
                              void* d_out, int out_size, void* d_ws, size_t ws_size,
                              hipStream_t stream) {
    const float* z     = (const float*)d_in[0];
    const int*   eidx  = (const int*)d_in[1];   // [2, E] flat: src then dst
    const int*   relid = (const int*)d_in[2];
    const float* rel   = (const float*)d_in[3];
    float*       out   = (float*)d_out;

    const int nz   = in_sizes[0];        // N_NODES * 128
    const int E    = in_sizes[2];        // 2,000,000
    const int nrel = in_sizes[3];        // 64 * 128
    const int nn   = nz / 128;           // N_NODES
    const int* src = eidx;
    const int* dst = eidx + E;

    // replica-region capacity: mean + ~8 sigma headroom, rounded to EPB
    const int mean_v = E / (NBKT * NREP);
    int vcap = mean_v + E / 16384 + 192;
    vcap = (vcap + EPB - 1) & ~(EPB - 1);        // 2304 for E=2M
    const int vcpb = vcap / EPB;                 // blocks per replica region

    // scatter blocks: 1024 baseline (4/CU), grow if E large
    int sc_blocks = (E + PE * 256 - 1) / (PE * 256);
    if (sc_blocks < 1024) sc_blocks = 1024;
    sc_blocks = (sc_blocks + NREP - 1) & ~(NREP - 1);

    const int n8z = nz / 8, n8r = nrel / 8;
    const int zc_blocks = (n8z + 255) / 256;
    const int rc_blocks = (n8r + 255) / 256;

    // ws layout
    const size_t sz_zh    = (size_t)nz * sizeof(__half);
    const size_t off_rh   = (sz_zh + 255) & ~(size_t)255;
    const size_t sz_rh    = (size_t)nrel * sizeof(__half);
    const size_t off_cnt  = (off_rh + sz_rh + 255) & ~(size_t)255;
    const size_t sz_cnt   = (size_t)NBKT * NREP * CNT_STRIDE * 4;   // 64 KB
    const size_t off_bin  = (off_cnt + sz_cnt + 255) & ~(size_t)255;
    const size_t sz_bin   = (size_t)NBKT * NREP * (size_t)vcap * 8;
    const size_t need     = off_bin + sz_bin;

    const bool rel_ok  = (nrel == 64 * 128);
    const bool bits_ok = (nn <= 131072) && (E <= (1 << 21)) && (nz % 8 == 0);

    if (ws_size >= need && rel_ok && bits_ok) {
        char* ws = (char*)d_ws;
        __half*   zh       = (__half*)(ws);
        __half*   rh       = (__half*)(ws + off_rh);
        uint32_t* counters = (uint32_t*)(ws + off_cnt);
        uint64_t* binned   = (uint64_t*)(ws + off_bin);

        hipMemsetAsync(counters, 0, sz_cnt, stream);
        const int aux_grid = sc_blocks + zc_blocks + rc_blocks;
        aux_merged_kernel<<<aux_grid, 256, 0, stream>>>(
            z, zh, n8z, rel, rh, n8r,
            src, dst, relid, E, nn, vcap, counters, binned,
            sc_blocks, zc_blocks);
        distmult_bucketed_v4_kernel<<<NSRC * NDST * NREP * vcpb, 256, 0, stream>>>(
            zh, binned, counters, rh, out, vcap, vcpb);
    } else if (ws_size >= off_rh + sz_rh && rel_ok && nz % 8 == 0) {
        __half* zh = (__half*)d_ws;
        __half* rh = (__half*)((char*)d_ws + off_rh);
        convert_kernel<<<zc_blocks, 256, 0, stream>>>(z, zh, n8z);
        convert_kernel<<<rc_blocks, 256, 0, stream>>>(rel, rh, n8r);
        const int groups = (E + 1) / 2;
        const int blocks = (groups * 16 + 255) / 256;
        distmult_f16_kernel<<<blocks, 256, 0, stream>>>(
            zh, src, dst, relid, rh, out, E);
    } else {
        const int blocks = (E * 16 + 255) / 256;
        distmult_f32_kernel<<<blocks, 256, 0, stream>>>(z, src, dst, relid, rel, out, E);
    }
}